// Round 11
// baseline (195.921 us; speedup 1.0000x reference)
//
#include <hip/hip_runtime.h>
#include <hip/hip_bf16.h>

// EGCL, MFMA, mixed weight storage + rcp activations + d2/adj broadcast.
// B=8, N=256, NF=H=128.
// edge_input@ew1 factorized: T0[i] + T1[j] + dist*ew1[256] + adj*ew1[257].
// Per block (one (b,i)): 256 threads = 4 waves, wave = h-QUARTER (32 h),
// covers all 64 j. j-tiles of 64, 4 iters, 4 barriers/tile.
// GEMM1: A = ew2T in VGPRs (32 regs); B = h1 from LDS.
// GEMM2: A = cw1T from LDS (32KB, staged ONCE); B = m from LDS.
// h1/m share one 16KB LDS buffer. {d2,adj} computed once per (i,j) by a
// tid<64 phase into d2a[] (broadcast), P1 maps 4h x 8j per thread.

#define BB 8
#define NN 256
#define HD 128
#define JT 64
#define NT (NN/JT)

typedef short bf16x8 __attribute__((ext_vector_type(8)));
typedef float f32x4  __attribute__((ext_vector_type(4)));

__device__ __forceinline__ float sigmoidf_(float x){
    return __builtin_amdgcn_rcpf(1.0f + __expf(-x));
}
__device__ __forceinline__ float siluf_(float x){
    return x * __builtin_amdgcn_rcpf(1.0f + __expf(-x));
}
__device__ __forceinline__ unsigned int cvtpk_bf16(float lo, float hi){
    unsigned int r;
    asm("v_cvt_pk_bf16_f32 %0, %1, %2" : "=v"(r) : "v"(lo), "v"(hi));
    return r;
}
__device__ __forceinline__ unsigned short f2bf(float x){
    unsigned int u = __float_as_uint(x);
    u += 0x7FFF + ((u>>16)&1);
    return (unsigned short)(u>>16);
}
__device__ __forceinline__ float bf2f(unsigned short h){
    return __uint_as_float(((unsigned int)h)<<16);
}

#define MFMA_BF16(d,a,b) d = __builtin_amdgcn_mfma_f32_16x16x32_bf16(a, b, d, 0, 0, 0)

// ---------- prep kernels ----------

__global__ __launch_bounds__(128) void precompute_T(
    const float* __restrict__ nf, const float* __restrict__ ew1,
    unsigned short* __restrict__ T0, unsigned short* __restrict__ T1)
{
    __shared__ float nfs[HD];
    const int bi = blockIdx.x;
    const int h  = threadIdx.x;
    nfs[h] = nf[(size_t)bi*HD + h];
    __syncthreads();
    float a0 = 0.f, a1 = 0.f;
    #pragma unroll 4
    for (int f = 0; f < HD; ++f){
        const float v = nfs[f];
        a0 = fmaf(v, ew1[f*HD + h],      a0);
        a1 = fmaf(v, ew1[(HD+f)*HD + h], a1);
    }
    T0[bi*HD + h] = f2bf(a0);
    T1[bi*HD + h] = f2bf(a1);
}

// wE: plain transposed bf16 ew2T [h][k] (consumed into registers).
// wC: transposed + XOR-swizzled cw1T (consumed by linear LDS copy + swizzled ds_read).
__global__ __launch_bounds__(256) void prep_w(
    const float* __restrict__ ew2, const float* __restrict__ cw1,
    unsigned short* __restrict__ dst)
{
    const int e = blockIdx.x*256 + threadIdx.x;   // 0..32767
    const int m = e >> 14;
    const int rem = e & 16383;
    const int h = rem >> 7, k = rem & 127;
    if (m == 0)
        dst[rem] = f2bf(ew2[k*HD + h]);                                  // plain
    else
        dst[16384 + ((((h<<7) | k) ^ ((h&7)<<3)))] = f2bf(cw1[k*HD + h]); // swizzled
}

// ---------- main kernel ----------

__global__ __launch_bounds__(256) void egcl_main(
    const float* __restrict__ nf,  const float* __restrict__ pos,
    const float* __restrict__ valid, const float* __restrict__ adj,
    const float* __restrict__ ew1,
    const float* __restrict__ cw2,
    const float* __restrict__ nw1, const float* __restrict__ nw2,
    const float* __restrict__ iw,
    const unsigned short* __restrict__ T0u, const unsigned short* __restrict__ T1u,
    const unsigned short* __restrict__ wE,  const unsigned short* __restrict__ wC,
    float* __restrict__ out)
{
    __shared__ unsigned short sW [16384];   // 32KB cw1T [h'][k] swizzled (staged once)
    __shared__ unsigned short sHM[JT*HD];   // 16KB shared: h1 [j][k] then m [j][h]
    __shared__ float gpartT[JT][4];         // transposed: one float4 per j
    __shared__ float cpartT[JT][4];
    __shared__ float2 d2a[JT];              // per-j {d2, adj} broadcast
    __shared__ float msgp[HD];
    __shared__ float red3[3];

    const int tid = threadIdx.x;
    const int bi  = blockIdx.x;
    const int b   = bi >> 8;
    const int wm  = tid >> 6;          // wave = h-quarter 0..3
    const int l   = tid & 63, lr = l & 15, lg = l >> 4;
    const int hp2 = tid & 31,  jq2 = tid >> 5;  // P1: 4 h x 8 j per thread
    const int hh  = tid & 127, half = tid >> 7; // node-MLP mapping

    // ---- stage cw1T into LDS ONCE (linear copy; data pre-swizzled) ----
    {
        const uint4* g = (const uint4*)wC;
        uint4* s = (uint4*)sW;
        #pragma unroll
        for (int r = 0; r < 8; ++r) s[r*256 + tid] = g[r*256 + tid];
    }

    // ---- ew2T A-fragments into registers ONCE (rows h = wm*32+mt*16+lr) ----
    bf16x8 aE[2][4];
    {
        const unsigned short* pE = wE + (((wm*32 + lr) << 7) + lg*8);
        #pragma unroll
        for (int mt = 0; mt < 2; ++mt)
            #pragma unroll
            for (int kk = 0; kk < 4; ++kk)
                aE[mt][kk] = *(const bf16x8*)(pE + (mt*16 << 7) + kk*32);
    }

    // ---- per-thread P1 constants (4 h's each) ----
    float4 t0v, w6v, w7v;
    {
        const ushort4 t0u4 = *(const ushort4*)&T0u[bi*HD + 4*hp2];
        t0v = make_float4(bf2f(t0u4.x), bf2f(t0u4.y), bf2f(t0u4.z), bf2f(t0u4.w));
        w6v = *(const float4*)&ew1[256*HD + 4*hp2];
        w7v = *(const float4*)&ew1[257*HD + 4*hp2];
    }
    const float pix = pos[bi*3+0], piy = pos[bi*3+1], piz = pos[bi*3+2];
    const float validi = valid[bi];
    const unsigned short* __restrict__ T1b = T1u + (size_t)(b*NN)*HD;
    const float* __restrict__ posb   = pos + (size_t)(b*NN)*3;
    const float* __restrict__ adjrow = adj + (size_t)bi*NN;

    float msgacc[8];
    #pragma unroll
    for (int s = 0; s < 8; ++s) msgacc[s] = 0.f;
    float pax = 0.f, pay = 0.f, paz = 0.f;   // tid<64 only

    // per-j {d2, adj} phase (tid<64), once per (i,j)
    #define D2A_PHASE(tt)                                          \
        if (tid < JT){                                             \
            const int j_ = (tt)*JT + tid;                          \
            const float dx_ = pix - posb[j_*3+0];                  \
            const float dy_ = piy - posb[j_*3+1];                  \
            const float dz_ = piz - posb[j_*3+2];                  \
            d2a[tid] = make_float2(dx_*dx_ + dy_*dy_ + dz_*dz_,    \
                                   adjrow[j_]);                    \
        }

    // ---- prologue: d2a for tile 0 (barrier also fences sW staging) ----
    D2A_PHASE(0)
    __syncthreads();   // P

    for (int t = 0; t < NT; ++t){
        const int j0 = t*JT;

        // ---- P1: h1 = silu(first-layer preact) -> sHM (bf16, swizzled) ----
        #pragma unroll
        for (int r = 0; r < 8; ++r){
            const int jl = jq2*8 + r;
            const float2 da = d2a[jl];
            const ushort4 t1v = *(const ushort4*)&T1b[(size_t)(j0+jl)*HD + 4*hp2];
            const float s0 = siluf_(fmaf(da.y, w7v.x, fmaf(da.x, w6v.x, t0v.x + bf2f(t1v.x))));
            const float s1 = siluf_(fmaf(da.y, w7v.y, fmaf(da.x, w6v.y, t0v.y + bf2f(t1v.y))));
            const float s2 = siluf_(fmaf(da.y, w7v.z, fmaf(da.x, w6v.z, t0v.z + bf2f(t1v.z))));
            const float s3 = siluf_(fmaf(da.y, w7v.w, fmaf(da.x, w6v.w, t0v.w + bf2f(t1v.w))));
            uint2 hv;
            hv.x = cvtpk_bf16(s0, s1);
            hv.y = cvtpk_bf16(s2, s3);
            *(uint2*)((unsigned int*)sHM + (((jl<<6) + 2*hp2) ^ ((jl&7)<<2))) = hv;
        }
        __syncthreads();   // A: h1 ready

        // ---- GEMM1: m = silu(ew2T @ h1T); A in regs, B from sHM ----
        f32x4 acc[2][4];
        #pragma unroll
        for (int mt = 0; mt < 2; ++mt)
            #pragma unroll
            for (int nt = 0; nt < 4; ++nt)
                acc[mt][nt] = (f32x4){0.f,0.f,0.f,0.f};
        {
            __builtin_amdgcn_s_setprio(1);
            #pragma unroll
            for (int kk = 0; kk < 4; ++kk){
                const int kb = kk*32 + lg*8;
                bf16x8 bf[4];
                #pragma unroll
                for (int nt = 0; nt < 4; ++nt){
                    const int jb = nt*16 + lr;
                    bf[nt] = *(const bf16x8*)&sHM[((jb<<7) + kb) ^ ((jb&7)<<3)];
                }
                #pragma unroll
                for (int mt = 0; mt < 2; ++mt)
                    #pragma unroll
                    for (int nt = 0; nt < 4; ++nt)
                        MFMA_BF16(acc[mt][nt], aE[mt][kk], bf[nt]);
            }
            __builtin_amdgcn_s_setprio(0);
        }
        __syncthreads();   // B: all waves done reading h1 -> sHM reusable

        // ---- GEMM1 epilogue: silu, gate partials, m -> sHM (overwrite) ----
        {
            float pg[4] = {0.f,0.f,0.f,0.f};
            #pragma unroll
            for (int mt = 0; mt < 2; ++mt){
                const f32x4 iwv = *(const f32x4*)&iw[wm*32 + mt*16 + lg*4];
                #pragma unroll
                for (int nt = 0; nt < 4; ++nt){
                    #pragma unroll
                    for (int i = 0; i < 4; ++i){
                        acc[mt][nt][i] = siluf_(acc[mt][nt][i]);
                        pg[nt] = fmaf(acc[mt][nt][i], iwv[i], pg[nt]);
                    }
                    const int jr = nt*16 + lr;
                    uint2 mv;
                    mv.x = cvtpk_bf16(acc[mt][nt][0], acc[mt][nt][1]);
                    mv.y = cvtpk_bf16(acc[mt][nt][2], acc[mt][nt][3]);
                    *(uint2*)&sHM[((jr<<7) + wm*32 + mt*16 + lg*4) ^ ((jr&7)<<3)] = mv;
                }
            }
            #pragma unroll
            for (int nt = 0; nt < 4; ++nt){
                pg[nt] += __shfl_xor(pg[nt], 16);
                pg[nt] += __shfl_xor(pg[nt], 32);
            }
            if (lg == 0){
                #pragma unroll
                for (int nt = 0; nt < 4; ++nt)
                    gpartT[nt*16 + lr][wm] = pg[nt];
            }
        }
        __syncthreads();   // C: m + gpartT ready

        // ---- gate (per-thread, float4 read) + msg accumulation from live m ----
        #pragma unroll
        for (int nt = 0; nt < 4; ++nt){
            const int jr = nt*16 + lr;
            const float4 g4 = *(const float4*)&gpartT[jr][0];
            const float g = sigmoidf_(g4.x + g4.y + g4.z + g4.w);
            #pragma unroll
            for (int mt = 0; mt < 2; ++mt)
                #pragma unroll
                for (int i = 0; i < 4; ++i)
                    msgacc[mt*4+i] = fmaf(acc[mt][nt][i], g, msgacc[mt*4+i]);
        }

        // ---- GEMM2: c1 = silu(cw1T @ mT); A from sW, B from sHM ----
        #pragma unroll
        for (int mt = 0; mt < 2; ++mt)
            #pragma unroll
            for (int nt = 0; nt < 4; ++nt)
                acc[mt][nt] = (f32x4){0.f,0.f,0.f,0.f};
        {
            __builtin_amdgcn_s_setprio(1);
            #pragma unroll
            for (int kk = 0; kk < 4; ++kk){
                const int kb = kk*32 + lg*8;
                bf16x8 af[2];
                #pragma unroll
                for (int mt = 0; mt < 2; ++mt){
                    const int hr = wm*32 + mt*16 + lr;
                    af[mt] = *(const bf16x8*)&sW[((hr<<7) + kb) ^ ((hr&7)<<3)];
                }
                bf16x8 bf[4];
                #pragma unroll
                for (int nt = 0; nt < 4; ++nt){
                    const int jb = nt*16 + lr;
                    bf[nt] = *(const bf16x8*)&sHM[((jb<<7) + kb) ^ ((jb&7)<<3)];
                }
                #pragma unroll
                for (int mt = 0; mt < 2; ++mt)
                    #pragma unroll
                    for (int nt = 0; nt < 4; ++nt)
                        MFMA_BF16(acc[mt][nt], af[mt], bf[nt]);
            }
            __builtin_amdgcn_s_setprio(0);
        }
        {
            float pc[4] = {0.f,0.f,0.f,0.f};
            #pragma unroll
            for (int mt = 0; mt < 2; ++mt){
                const f32x4 cwv = *(const f32x4*)&cw2[wm*32 + mt*16 + lg*4];
                #pragma unroll
                for (int nt = 0; nt < 4; ++nt)
                    #pragma unroll
                    for (int i = 0; i < 4; ++i)
                        pc[nt] = fmaf(siluf_(acc[mt][nt][i]), cwv[i], pc[nt]);
            }
            #pragma unroll
            for (int nt = 0; nt < 4; ++nt){
                pc[nt] += __shfl_xor(pc[nt], 16);
                pc[nt] += __shfl_xor(pc[nt], 32);
            }
            if (lg == 0){
                #pragma unroll
                for (int nt = 0; nt < 4; ++nt)
                    cpartT[nt*16 + lr][wm] = pc[nt];
            }
        }

        // ---- d2a for next tile (before D so P1(t+1) reads are fenced) ----
        if (t < NT-1) D2A_PHASE(t+1)
        __syncthreads();   // D: cpartT + d2a(t+1) ready; sHM m-reads done

        // ---- pos accumulation (threads 0..63, one j each) ----
        if (tid < JT){
            const float4 c4 = *(const float4*)&cpartT[tid][0];
            const float c = c4.x + c4.y + c4.z + c4.w;
            const int j = j0 + tid;
            const float pjx = posb[j*3+0], pjy = posb[j*3+1], pjz = posb[j*3+2];
            const float dx = pix-pjx, dy = piy-pjy, dz = piz-pjz;
            const float d2 = dx*dx + dy*dy + dz*dz;
            const float nrm = __builtin_amdgcn_sqrtf(d2);
            const float inv = __builtin_amdgcn_rcpf(fmaxf(nrm, 1e-10f));
            const float cd = c * inv;
            pax = fmaf(dx, cd, pax);
            pay = fmaf(dy, cd, pay);
            paz = fmaf(dz, cd, paz);
        }
        // hazards: sHM h1-writes(t+1) vs m-reads(t): fenced by D(t);
        // gpartT write(t+1) [after B(t+1)] vs read(t) [after C(t)]: fenced;
        // cpartT write(t+1) [after C(t+1)] vs read(t) [after D(t)]: fenced;
        // d2a write(t+1) [before D(t)] vs P1 read(t) [before A(t)]: fenced.
    }

    // ---- finalize msg: reduce over lr (j) lanes; each h owned by one wave ----
    #pragma unroll
    for (int s = 0; s < 8; ++s){
        msgacc[s] += __shfl_xor(msgacc[s], 1);
        msgacc[s] += __shfl_xor(msgacc[s], 2);
        msgacc[s] += __shfl_xor(msgacc[s], 4);
        msgacc[s] += __shfl_xor(msgacc[s], 8);
    }
    if (lr == 0){
        #pragma unroll
        for (int mt = 0; mt < 2; ++mt)
            #pragma unroll
            for (int i = 0; i < 4; ++i)
                msgp[wm*32 + mt*16 + lg*4 + i] = msgacc[mt*4+i];
    }

    // ---- finalize pos: wave-0 reduce ----
    if (wm == 0){
        float sx = pax, sy = pay, sz = paz;
        #pragma unroll
        for (int off = 1; off <= 32; off <<= 1){
            sx += __shfl_xor(sx, off);
            sy += __shfl_xor(sy, off);
            sz += __shfl_xor(sz, off);
        }
        if (l == 0){ red3[0] = sx; red3[1] = sy; red3[2] = sz; }
    }
    __syncthreads();   // msgp + red3 ready; sW reads all done -> alias below

    // ---- node MLP scratch aliases the sW region (sW no longer needed) ----
    float* nbuf = (float*)sW;           // ni[256] | n1l[128] | np2[2][128]
    float* ni   = nbuf;
    float* n1l  = nbuf + 256;
    float* np2  = nbuf + 384;

    const float scale = validi * (1.0f/NN);
    if (tid < HD){
        ni[tid]      = nf[(size_t)bi*HD + tid];
        ni[HD + tid] = msgp[tid] * scale;
    }
    if (tid == 0){
        out[(size_t)bi*3+0] = pix + red3[0]*scale;
        out[(size_t)bi*3+1] = piy + red3[1]*scale;
        out[(size_t)bi*3+2] = piz + red3[2]*scale;
    }
    __syncthreads();

    // ---- node MLP (fp32, K split across halves) ----
    float p1 = 0.f;
    for (int f = 0; f < HD; ++f){
        const int ff = half*HD + f;
        p1 = fmaf(ni[ff], nw1[ff*HD + hh], p1);
    }
    np2[half*HD + hh] = p1;
    __syncthreads();
    if (tid < HD) n1l[tid] = siluf_(np2[tid] + np2[HD + tid]);
    __syncthreads();
    float p2 = 0.f;
    for (int k = 0; k < 64; ++k){
        const int kk2 = half*64 + k;
        p2 = fmaf(n1l[kk2], nw2[kk2*HD + hh], p2);
    }
    np2[half*HD + hh] = p2;
    __syncthreads();
    if (tid < HD){
        out[(size_t)BB*NN*3 + (size_t)bi*HD + tid] =
            nf[(size_t)bi*HD + tid] + np2[tid] + np2[HD + tid];
    }
}

extern "C" void kernel_launch(void* const* d_in, const int* in_sizes, int n_in,
                              void* d_out, int out_size, void* d_ws, size_t ws_size,
                              hipStream_t stream)
{
    const float* nf    = (const float*)d_in[0];
    const float* pos   = (const float*)d_in[1];
    const float* valid = (const float*)d_in[2];
    const float* adj   = (const float*)d_in[3];
    const float* ew1   = (const float*)d_in[4];
    const float* ew2   = (const float*)d_in[5];
    const float* cw1   = (const float*)d_in[6];
    const float* cw2   = (const float*)d_in[7];
    const float* nw1   = (const float*)d_in[8];
    const float* nw2   = (const float*)d_in[9];
    const float* iw    = (const float*)d_in[10];
    float* out = (float*)d_out;

    // ws layout: wE(32KB) | wC(32KB) | T0(512KB) | T1(512KB)
    unsigned short* wE  = (unsigned short*)d_ws;
    unsigned short* wC  = wE + 16384;
    unsigned short* T0u = wC + 16384;
    unsigned short* T1u = T0u + (size_t)BB*NN*HD;

    hipLaunchKernelGGL(prep_w, dim3(128), dim3(256), 0, stream, ew2, cw1, wE);
    hipLaunchKernelGGL(precompute_T, dim3(BB*NN), dim3(HD), 0, stream,
                       nf, ew1, T0u, T1u);
    hipLaunchKernelGGL(egcl_main, dim3(BB*NN), dim3(256), 0, stream,
                       nf, pos, valid, adj, ew1, cw2, nw1, nw2, iw,
                       T0u, T1u, wE, wC, out);
}

// Round 12
// 154.937 us; speedup vs baseline: 1.2645x; 1.2645x over previous
//
#include <hip/hip_runtime.h>
#include <hip/hip_bf16.h>

// EGCL, MFMA, mixed weight storage + rcp activations + reg-neutral d2a broadcast.
// B=8, N=256, NF=H=128.
// edge_input@ew1 factorized: T0[i] + T1[j] + dist*ew1[256] + adj*ew1[257].
// Per block (one (b,i)): 256 threads = 4 waves, wave = h-QUARTER (32 h),
// covers all 64 j. j-tiles of 64, 4 iters, 4 barriers/tile.
// GEMM1: A = ew2T in VGPRs (32 regs); B = h1 from LDS.
// GEMM2: A = cw1T from LDS (32KB, staged ONCE); B = m from LDS.
// h1/m share one 16KB LDS buffer. {d2,adj} computed once per (i,j) by a
// tid<64 phase into d2a[] (broadcast); P1 keeps the 2h x 16j mapping
// and scalar constants (REGISTER-NEUTRAL vs the 153us baseline).

#define BB 8
#define NN 256
#define HD 128
#define JT 64
#define NT (NN/JT)

typedef short bf16x8 __attribute__((ext_vector_type(8)));
typedef float f32x4  __attribute__((ext_vector_type(4)));

__device__ __forceinline__ float sigmoidf_(float x){
    return __builtin_amdgcn_rcpf(1.0f + __expf(-x));
}
__device__ __forceinline__ float siluf_(float x){
    return x * __builtin_amdgcn_rcpf(1.0f + __expf(-x));
}
__device__ __forceinline__ unsigned int cvtpk_bf16(float lo, float hi){
    unsigned int r;
    asm("v_cvt_pk_bf16_f32 %0, %1, %2" : "=v"(r) : "v"(lo), "v"(hi));
    return r;
}
__device__ __forceinline__ unsigned short f2bf(float x){
    unsigned int u = __float_as_uint(x);
    u += 0x7FFF + ((u>>16)&1);
    return (unsigned short)(u>>16);
}
__device__ __forceinline__ float bf2f(unsigned short h){
    return __uint_as_float(((unsigned int)h)<<16);
}

#define MFMA_BF16(d,a,b) d = __builtin_amdgcn_mfma_f32_16x16x32_bf16(a, b, d, 0, 0, 0)

// ---------- prep kernels ----------

__global__ __launch_bounds__(128) void precompute_T(
    const float* __restrict__ nf, const float* __restrict__ ew1,
    unsigned short* __restrict__ T0, unsigned short* __restrict__ T1)
{
    __shared__ float nfs[HD];
    const int bi = blockIdx.x;
    const int h  = threadIdx.x;
    nfs[h] = nf[(size_t)bi*HD + h];
    __syncthreads();
    float a0 = 0.f, a1 = 0.f;
    #pragma unroll 4
    for (int f = 0; f < HD; ++f){
        const float v = nfs[f];
        a0 = fmaf(v, ew1[f*HD + h],      a0);
        a1 = fmaf(v, ew1[(HD+f)*HD + h], a1);
    }
    T0[bi*HD + h] = f2bf(a0);
    T1[bi*HD + h] = f2bf(a1);
}

// wE: plain transposed bf16 ew2T [h][k] (consumed into registers).
// wC: transposed + XOR-swizzled cw1T (consumed by linear LDS copy + swizzled ds_read).
__global__ __launch_bounds__(256) void prep_w(
    const float* __restrict__ ew2, const float* __restrict__ cw1,
    unsigned short* __restrict__ dst)
{
    const int e = blockIdx.x*256 + threadIdx.x;   // 0..32767
    const int m = e >> 14;
    const int rem = e & 16383;
    const int h = rem >> 7, k = rem & 127;
    if (m == 0)
        dst[rem] = f2bf(ew2[k*HD + h]);                                  // plain
    else
        dst[16384 + ((((h<<7) | k) ^ ((h&7)<<3)))] = f2bf(cw1[k*HD + h]); // swizzled
}

// ---------- main kernel ----------

__global__ __launch_bounds__(256) void egcl_main(
    const float* __restrict__ nf,  const float* __restrict__ pos,
    const float* __restrict__ valid, const float* __restrict__ adj,
    const float* __restrict__ ew1,
    const float* __restrict__ cw2,
    const float* __restrict__ nw1, const float* __restrict__ nw2,
    const float* __restrict__ iw,
    const unsigned short* __restrict__ T0u, const unsigned short* __restrict__ T1u,
    const unsigned short* __restrict__ wE,  const unsigned short* __restrict__ wC,
    float* __restrict__ out)
{
    __shared__ unsigned short sW [16384];   // 32KB cw1T [h'][k] swizzled (staged once)
    __shared__ unsigned short sHM[JT*HD];   // 16KB shared: h1 [j][k] then m [j][h]
    __shared__ float gpart[4][JT];
    __shared__ float cpart[4][JT];
    __shared__ float2 d2a[JT];              // per-j {d2, adj} broadcast
    __shared__ float msgp[HD];
    __shared__ float red3[3];

    const int tid = threadIdx.x;
    const int bi  = blockIdx.x;
    const int b   = bi >> 8;
    const int wm  = tid >> 6;          // wave = h-quarter 0..3
    const int l   = tid & 63, lr = l & 15, lg = l >> 4;
    const int hp  = tid & 63,  jq = tid >> 6;   // P1 mapping: 2 h x 16 j per thread
    const int hh  = tid & 127, half = tid >> 7; // node-MLP mapping

    // ---- stage cw1T into LDS ONCE (linear copy; data pre-swizzled) ----
    {
        const uint4* g = (const uint4*)wC;
        uint4* s = (uint4*)sW;
        #pragma unroll
        for (int r = 0; r < 8; ++r) s[r*256 + tid] = g[r*256 + tid];
    }

    // ---- ew2T A-fragments into registers ONCE (rows h = wm*32+mt*16+lr) ----
    bf16x8 aE[2][4];
    {
        const unsigned short* pE = wE + (((wm*32 + lr) << 7) + lg*8);
        #pragma unroll
        for (int mt = 0; mt < 2; ++mt)
            #pragma unroll
            for (int kk = 0; kk < 4; ++kk)
                aE[mt][kk] = *(const bf16x8*)(pE + (mt*16 << 7) + kk*32);
    }

    // ---- per-thread P1 constants (scalar, register-neutral) ----
    const float t0a = bf2f(T0u[bi*HD + 2*hp]);
    const float t0b = bf2f(T0u[bi*HD + 2*hp + 1]);
    const float w6a = ew1[256*HD + 2*hp], w6b = ew1[256*HD + 2*hp + 1];
    const float w7a = ew1[257*HD + 2*hp], w7b = ew1[257*HD + 2*hp + 1];
    const float pix = pos[bi*3+0], piy = pos[bi*3+1], piz = pos[bi*3+2];
    const float validi = valid[bi];
    const unsigned short* __restrict__ T1b = T1u + (size_t)(b*NN)*HD;
    const float* __restrict__ posb   = pos + (size_t)(b*NN)*3;
    const float* __restrict__ adjrow = adj + (size_t)bi*NN;

    float msgacc[8];
    #pragma unroll
    for (int s = 0; s < 8; ++s) msgacc[s] = 0.f;
    float pax = 0.f, pay = 0.f, paz = 0.f;   // tid<64 only

    // per-j {d2, adj} phase (tid<64), once per (i,j)
    #define D2A_PHASE(tt)                                          \
        if (tid < JT){                                             \
            const int j_ = (tt)*JT + tid;                          \
            const float dx_ = pix - posb[j_*3+0];                  \
            const float dy_ = piy - posb[j_*3+1];                  \
            const float dz_ = piz - posb[j_*3+2];                  \
            d2a[tid] = make_float2(dx_*dx_ + dy_*dy_ + dz_*dz_,    \
                                   adjrow[j_]);                    \
        }

    // ---- prologue: d2a for tile 0 (barrier also fences sW staging) ----
    D2A_PHASE(0)
    __syncthreads();   // P

    for (int t = 0; t < NT; ++t){
        const int j0 = t*JT;

        // ---- P1: h1 = silu(first-layer preact) -> sHM (bf16, swizzled) ----
        #pragma unroll 2
        for (int r = 0; r < 16; ++r){
            const int jl = jq*16 + r;
            const int j  = j0 + jl;
            const float2 da = d2a[jl];
            const ushort2 t1v = *(const ushort2*)&T1b[(size_t)j*HD + 2*hp];
            const float s0 = siluf_(fmaf(da.y, w7a, fmaf(da.x, w6a, t0a + bf2f(t1v.x))));
            const float s1 = siluf_(fmaf(da.y, w7b, fmaf(da.x, w6b, t0b + bf2f(t1v.y))));
            ((unsigned int*)sHM)[(jl*64 + hp) ^ ((jl&7)<<2)] = cvtpk_bf16(s0, s1);
        }
        __syncthreads();   // A: h1 ready

        // ---- GEMM1: m = silu(ew2T @ h1T); A in regs, B from sHM ----
        f32x4 acc[2][4];
        #pragma unroll
        for (int mt = 0; mt < 2; ++mt)
            #pragma unroll
            for (int nt = 0; nt < 4; ++nt)
                acc[mt][nt] = (f32x4){0.f,0.f,0.f,0.f};
        {
            __builtin_amdgcn_s_setprio(1);
            #pragma unroll
            for (int kk = 0; kk < 4; ++kk){
                const int kb = kk*32 + lg*8;
                bf16x8 bf[4];
                #pragma unroll
                for (int nt = 0; nt < 4; ++nt){
                    const int jb = nt*16 + lr;
                    bf[nt] = *(const bf16x8*)&sHM[((jb<<7) + kb) ^ ((jb&7)<<3)];
                }
                #pragma unroll
                for (int mt = 0; mt < 2; ++mt)
                    #pragma unroll
                    for (int nt = 0; nt < 4; ++nt)
                        MFMA_BF16(acc[mt][nt], aE[mt][kk], bf[nt]);
            }
            __builtin_amdgcn_s_setprio(0);
        }
        __syncthreads();   // B: all waves done reading h1 -> sHM reusable

        // ---- GEMM1 epilogue: silu, gate partials, m -> sHM (overwrite) ----
        {
            float pg[4] = {0.f,0.f,0.f,0.f};
            #pragma unroll
            for (int mt = 0; mt < 2; ++mt){
                const f32x4 iwv = *(const f32x4*)&iw[wm*32 + mt*16 + lg*4];
                #pragma unroll
                for (int nt = 0; nt < 4; ++nt){
                    #pragma unroll
                    for (int i = 0; i < 4; ++i){
                        acc[mt][nt][i] = siluf_(acc[mt][nt][i]);
                        pg[nt] = fmaf(acc[mt][nt][i], iwv[i], pg[nt]);
                    }
                    const int jr = nt*16 + lr;
                    uint2 mv;
                    mv.x = cvtpk_bf16(acc[mt][nt][0], acc[mt][nt][1]);
                    mv.y = cvtpk_bf16(acc[mt][nt][2], acc[mt][nt][3]);
                    *(uint2*)&sHM[((jr<<7) + wm*32 + mt*16 + lg*4) ^ ((jr&7)<<3)] = mv;
                }
            }
            #pragma unroll
            for (int nt = 0; nt < 4; ++nt){
                pg[nt] += __shfl_xor(pg[nt], 16);
                pg[nt] += __shfl_xor(pg[nt], 32);
            }
            if (lg == 0){
                #pragma unroll
                for (int nt = 0; nt < 4; ++nt)
                    gpart[wm][nt*16 + lr] = pg[nt];
            }
        }
        __syncthreads();   // C: m + gpart ready

        // ---- gate (per-thread, redundant) + msg accumulation from live m ----
        #pragma unroll
        for (int nt = 0; nt < 4; ++nt){
            const int jr = nt*16 + lr;
            const float g = sigmoidf_(gpart[0][jr]+gpart[1][jr]+gpart[2][jr]+gpart[3][jr]);
            #pragma unroll
            for (int mt = 0; mt < 2; ++mt)
                #pragma unroll
                for (int i = 0; i < 4; ++i)
                    msgacc[mt*4+i] = fmaf(acc[mt][nt][i], g, msgacc[mt*4+i]);
        }

        // ---- GEMM2: c1 = silu(cw1T @ mT); A from sW, B from sHM ----
        #pragma unroll
        for (int mt = 0; mt < 2; ++mt)
            #pragma unroll
            for (int nt = 0; nt < 4; ++nt)
                acc[mt][nt] = (f32x4){0.f,0.f,0.f,0.f};
        {
            __builtin_amdgcn_s_setprio(1);
            #pragma unroll
            for (int kk = 0; kk < 4; ++kk){
                const int kb = kk*32 + lg*8;
                bf16x8 af[2];
                #pragma unroll
                for (int mt = 0; mt < 2; ++mt){
                    const int hr = wm*32 + mt*16 + lr;
                    af[mt] = *(const bf16x8*)&sW[((hr<<7) + kb) ^ ((hr&7)<<3)];
                }
                bf16x8 bf[4];
                #pragma unroll
                for (int nt = 0; nt < 4; ++nt){
                    const int jb = nt*16 + lr;
                    bf[nt] = *(const bf16x8*)&sHM[((jb<<7) + kb) ^ ((jb&7)<<3)];
                }
                #pragma unroll
                for (int mt = 0; mt < 2; ++mt)
                    #pragma unroll
                    for (int nt = 0; nt < 4; ++nt)
                        MFMA_BF16(acc[mt][nt], af[mt], bf[nt]);
            }
            __builtin_amdgcn_s_setprio(0);
        }
        {
            float pc[4] = {0.f,0.f,0.f,0.f};
            #pragma unroll
            for (int mt = 0; mt < 2; ++mt){
                const f32x4 cwv = *(const f32x4*)&cw2[wm*32 + mt*16 + lg*4];
                #pragma unroll
                for (int nt = 0; nt < 4; ++nt)
                    #pragma unroll
                    for (int i = 0; i < 4; ++i)
                        pc[nt] = fmaf(siluf_(acc[mt][nt][i]), cwv[i], pc[nt]);
            }
            #pragma unroll
            for (int nt = 0; nt < 4; ++nt){
                pc[nt] += __shfl_xor(pc[nt], 16);
                pc[nt] += __shfl_xor(pc[nt], 32);
            }
            if (lg == 0){
                #pragma unroll
                for (int nt = 0; nt < 4; ++nt)
                    cpart[wm][nt*16 + lr] = pc[nt];
            }
        }

        // ---- d2a for next tile (between C and D: fenced both ways) ----
        if (t < NT-1) D2A_PHASE(t+1)
        __syncthreads();   // D: cpart + d2a(t+1) ready; sHM m-reads done

        // ---- pos accumulation (threads 0..63, one j each) ----
        if (tid < JT){
            const float c = cpart[0][tid] + cpart[1][tid] + cpart[2][tid] + cpart[3][tid];
            const int j = j0 + tid;
            const float pjx = posb[j*3+0], pjy = posb[j*3+1], pjz = posb[j*3+2];
            const float dx = pix-pjx, dy = piy-pjy, dz = piz-pjz;
            const float d2 = dx*dx + dy*dy + dz*dz;
            const float nrm = __builtin_amdgcn_sqrtf(d2);
            const float inv = __builtin_amdgcn_rcpf(fmaxf(nrm, 1e-10f));
            const float cd = c * inv;
            pax = fmaf(dx, cd, pax);
            pay = fmaf(dy, cd, pay);
            paz = fmaf(dz, cd, paz);
        }
        // hazards: sHM h1-writes(t+1) vs m-reads(t): fenced by D(t);
        // gpart write(t+1) [after B(t+1)] vs read(t) [after C(t)]: fenced;
        // cpart write(t+1) [after C(t+1)] vs read(t) [after D(t)]: fenced;
        // d2a write(t+1) [C(t)..D(t)] vs P1 reads(t) [before A(t)]: fenced;
        // d2a reads(t+1) [after D(t)]: fenced.
    }

    // ---- finalize msg: reduce over lr (j) lanes; each h owned by one wave ----
    #pragma unroll
    for (int s = 0; s < 8; ++s){
        msgacc[s] += __shfl_xor(msgacc[s], 1);
        msgacc[s] += __shfl_xor(msgacc[s], 2);
        msgacc[s] += __shfl_xor(msgacc[s], 4);
        msgacc[s] += __shfl_xor(msgacc[s], 8);
    }
    if (lr == 0){
        #pragma unroll
        for (int mt = 0; mt < 2; ++mt)
            #pragma unroll
            for (int i = 0; i < 4; ++i)
                msgp[wm*32 + mt*16 + lg*4 + i] = msgacc[mt*4+i];
    }

    // ---- finalize pos: wave-0 reduce ----
    if (wm == 0){
        float sx = pax, sy = pay, sz = paz;
        #pragma unroll
        for (int off = 1; off <= 32; off <<= 1){
            sx += __shfl_xor(sx, off);
            sy += __shfl_xor(sy, off);
            sz += __shfl_xor(sz, off);
        }
        if (l == 0){ red3[0] = sx; red3[1] = sy; red3[2] = sz; }
    }
    __syncthreads();   // msgp + red3 ready; sW reads all done -> alias below

    // ---- node MLP scratch aliases the sW region (sW no longer needed) ----
    float* nbuf = (float*)sW;           // ni[256] | n1l[128] | np2[2][128]
    float* ni   = nbuf;
    float* n1l  = nbuf + 256;
    float* np2  = nbuf + 384;

    const float scale = validi * (1.0f/NN);
    if (tid < HD){
        ni[tid]      = nf[(size_t)bi*HD + tid];
        ni[HD + tid] = msgp[tid] * scale;
    }
    if (tid == 0){
        out[(size_t)bi*3+0] = pix + red3[0]*scale;
        out[(size_t)bi*3+1] = piy + red3[1]*scale;
        out[(size_t)bi*3+2] = piz + red3[2]*scale;
    }
    __syncthreads();

    // ---- node MLP (fp32, K split across halves) ----
    float p1 = 0.f;
    for (int f = 0; f < HD; ++f){
        const int ff = half*HD + f;
        p1 = fmaf(ni[ff], nw1[ff*HD + hh], p1);
    }
    np2[half*HD + hh] = p1;
    __syncthreads();
    if (tid < HD) n1l[tid] = siluf_(np2[tid] + np2[HD + tid]);
    __syncthreads();
    float p2 = 0.f;
    for (int k = 0; k < 64; ++k){
        const int kk2 = half*64 + k;
        p2 = fmaf(n1l[kk2], nw2[kk2*HD + hh], p2);
    }
    np2[half*HD + hh] = p2;
    __syncthreads();
    if (tid < HD){
        out[(size_t)BB*NN*3 + (size_t)bi*HD + tid] =
            nf[(size_t)bi*HD + tid] + np2[tid] + np2[HD + tid];
    }
}

extern "C" void kernel_launch(void* const* d_in, const int* in_sizes, int n_in,
                              void* d_out, int out_size, void* d_ws, size_t ws_size,
                              hipStream_t stream)
{
    const float* nf    = (const float*)d_in[0];
    const float* pos   = (const float*)d_in[1];
    const float* valid = (const float*)d_in[2];
    const float* adj   = (const float*)d_in[3];
    const float* ew1   = (const float*)d_in[4];
    const float* ew2   = (const float*)d_in[5];
    const float* cw1   = (const float*)d_in[6];
    const float* cw2   = (const float*)d_in[7];
    const float* nw1   = (const float*)d_in[8];
    const float* nw2   = (const float*)d_in[9];
    const float* iw    = (const float*)d_in[10];
    float* out = (float*)d_out;

    // ws layout: wE(32KB) | wC(32KB) | T0(512KB) | T1(512KB)
    unsigned short* wE  = (unsigned short*)d_ws;
    unsigned short* wC  = wE + 16384;
    unsigned short* T0u = wC + 16384;
    unsigned short* T1u = T0u + (size_t)BB*NN*HD;

    hipLaunchKernelGGL(prep_w, dim3(128), dim3(256), 0, stream, ew2, cw1, wE);
    hipLaunchKernelGGL(precompute_T, dim3(BB*NN), dim3(HD), 0, stream,
                       nf, ew1, T0u, T1u);
    hipLaunchKernelGGL(egcl_main, dim3(BB*NN), dim3(256), 0, stream,
                       nf, pos, valid, adj, ew1, cw2, nw1, nw2, iw,
                       T0u, T1u, wE, wC, out);
}